// Round 4
// baseline (633.834 us; speedup 1.0000x reference)
//
#include <hip/hip_runtime.h>
#include <hip/hip_bf16.h>
#include <stdint.h>

#define IN_DIM  4096
#define OUT_DIM 4096
#define M_DIM   16384   // 8*2048
#define BK      64
#define NT      (IN_DIM / BK)   // 64

typedef float f32x4 __attribute__((ext_vector_type(4)));
typedef short bf16x8 __attribute__((ext_vector_type(8)));
typedef short bf16x4 __attribute__((ext_vector_type(4)));
typedef int   i32x4 __attribute__((ext_vector_type(4)));

__device__ __constant__ float NF4_CODE_D[16] = {
    -1.0f, -0.6961928009986877f, -0.5250730514526367f, -0.39491748809814453f,
    -0.28444138169288635f, -0.18477343022823334f, -0.09105003625154495f, 0.0f,
    0.07958029955625534f, 0.16093020141124725f, 0.24611230194568634f,
    0.33791524171829224f, 0.44070982933044434f, 0.5626170039176941f,
    0.7229568362236023f, 1.0f};

static __device__ __forceinline__ ushort f2bf(float f) {
  union { float f; uint32_t u; } v; v.f = f;
  uint32_t r = v.u + 0x7FFFu + ((v.u >> 16) & 1u);
  return (ushort)(r >> 16);
}

// ---------------- dequant: qweight(int32 0..15) * absmax -> bf16 W[N][K] ----
__global__ void dequant_nf4(const int* __restrict__ q, const float* __restrict__ am,
                            ushort* __restrict__ w) {
  __shared__ float code[16];
  if (threadIdx.x < 16) code[threadIdx.x] = NF4_CODE_D[threadIdx.x];
  __syncthreads();
  size_t t = (size_t)blockIdx.x * blockDim.x + threadIdx.x;
  size_t base = t * 8;
  i32x4 qa = *(const i32x4*)(q + base);
  i32x4 qb = *(const i32x4*)(q + base + 4);
  float s = am[base >> 6];
  bf16x8 o;
  o[0] = (short)f2bf(code[qa[0] & 15] * s);
  o[1] = (short)f2bf(code[qa[1] & 15] * s);
  o[2] = (short)f2bf(code[qa[2] & 15] * s);
  o[3] = (short)f2bf(code[qa[3] & 15] * s);
  o[4] = (short)f2bf(code[qb[0] & 15] * s);
  o[5] = (short)f2bf(code[qb[1] & 15] * s);
  o[6] = (short)f2bf(code[qb[2] & 15] * s);
  o[7] = (short)f2bf(code[qb[3] & 15] * s);
  *(bf16x8*)(w + base) = o;
}

// ---------------- x fp32 -> bf16 ----------------
__global__ void cvt_x(const float* __restrict__ x, ushort* __restrict__ xb) {
  size_t t = (size_t)blockIdx.x * blockDim.x + threadIdx.x;
  size_t base = t * 8;
  f32x4 a = *(const f32x4*)(x + base);
  f32x4 b = *(const f32x4*)(x + base + 4);
  bf16x8 o;
  o[0] = (short)f2bf(a[0]); o[1] = (short)f2bf(a[1]);
  o[2] = (short)f2bf(a[2]); o[3] = (short)f2bf(a[3]);
  o[4] = (short)f2bf(b[0]); o[5] = (short)f2bf(b[1]);
  o[6] = (short)f2bf(b[2]); o[7] = (short)f2bf(b[3]);
  *(bf16x8*)(xb + base) = o;
}

// ---------------- global_load_lds helper (16B direct-to-LDS) ---------------
static __device__ __forceinline__ void llds16(const ushort* g, ushort* l) {
  __builtin_amdgcn_global_load_lds(
      (const __attribute__((address_space(1))) void*)g,
      (__attribute__((address_space(3))) void*)l, 16, 0, 0);
}

// ===========================================================================
// 256x256 GEMM, deep-pipelined 4-phase schedule (stage 2 K-tiles ahead).
// y[M][N] = Xb[M][K] * W[N][K]^T, bf16 MFMA 16x16x32, 8 waves (2Mx4N).
// Per-wave output: rows {wr*64} U {128+wr*64}, cols {wc*32} U {128+wc*32}.
// Per K-tile t (barrier at end of each phase):
//  P1: read b1,aB[cur];                    Q00(aA,b0);  bar  (publishes A0,B0
//      reads of cur done)
//  P2: ST A0(t+2),B0(t+2)->cur;            Q01(aA,b1);  bar
//  P3:                                     Q11(aB,b1);  bar  (publishes A1,B1
//      reads of cur done)
//  P4: ST A1(t+2),B1(t+2)->cur; VMC(8); bar; Q10(aB,b0); read aA,b0[nxt]
// WAR legality: t+2's writes into cur land after the barrier that publishes
// the last ds_read of the region's previous contents (A0/B0 end-P1, A1/B1
// end-P3). vmcnt ledger (2 loads/region/wave): at P4 outstanding = 8 (all of
// t+2); older = t+1's 8, staged at P2/P4 of t-1 -> 6-8 phases of flight
// (~900-1600cy) covers HBM/L3 latency. ONE vmcnt(8) per tile, never 0 in loop.
// Swizzle (T2): LDS slot s of row r holds global slot s^(r&7); applied on
// the global source col at staging and on the ds_read address (rule #21).
// ===========================================================================
__global__ __launch_bounds__(512, 2) void gemm256(const ushort* __restrict__ Xb,
                                                  const ushort* __restrict__ W,
                                                  float* __restrict__ Y) {
  __shared__ ushort As[2][256 * BK];   // 2 x 32 KB
  __shared__ ushort Bs[2][256 * BK];   // 2 x 32 KB

  const int tid  = threadIdx.x;
  const int lane = tid & 63;
  const int wid  = tid >> 6;        // 0..7
  const int wr   = wid >> 2;        // 0..1
  const int wc   = wid & 3;         // 0..3
  const int l15  = lane & 15;
  const int kg   = lane >> 4;       // 0..3
  const int l7   = lane & 7;

  // bijective XCD swizzle (1024 wgs, 1024%8==0), tn-major within tm.
  const int bid = blockIdx.x;
  const int wg  = (bid & 7) * 128 + (bid >> 3);
  const int tm  = wg >> 4;          // 0..63
  const int tn  = wg & 15;          // 0..15
  const size_t row0 = (size_t)tm * 256;
  const size_t col0 = (size_t)tn * 256;

  const int srow  = tid >> 3;                       // 0..63
  const int scol8 = ((tid & 7) ^ (srow & 7)) * 8;   // pre-swizzled src col
  const int wbase = wid << 9;                       // wave LDS base (ushorts)

  f32x4  acc[8][4] = {};
  bf16x8 aA[4][2], aB[4][2], b0[2][2], b1[2][2];

#define BARX()  __builtin_amdgcn_s_barrier()
#define VMC(n)  asm volatile("s_waitcnt vmcnt(" #n ")" ::: "memory")
#define PRI1()  __builtin_amdgcn_s_setprio(1)
#define PRI0()  __builtin_amdgcn_s_setprio(0)

#define STAGE_A(kt, h, nb) do { \
    llds16(Xb + (row0 + (h)*128 +  0 + srow) * IN_DIM + (kt)*BK + scol8, \
           &As[nb][(h)*8192 +    0 + wbase]); \
    llds16(Xb + (row0 + (h)*128 + 64 + srow) * IN_DIM + (kt)*BK + scol8, \
           &As[nb][(h)*8192 + 4096 + wbase]); \
  } while (0)

#define STAGE_B(kt, h, nb) do { \
    llds16(W + (col0 + (h)*128 +  0 + srow) * IN_DIM + (kt)*BK + scol8, \
           &Bs[nb][(h)*8192 +    0 + wbase]); \
    llds16(W + (col0 + (h)*128 + 64 + srow) * IN_DIM + (kt)*BK + scol8, \
           &Bs[nb][(h)*8192 + 4096 + wbase]); \
  } while (0)

#define LDA_(dst, nb, mh) do { \
    _Pragma("unroll") for (int mi = 0; mi < 4; ++mi) \
    _Pragma("unroll") for (int ks = 0; ks < 2; ++ks) \
      dst[mi][ks] = *(const bf16x8*)&As[nb][((mh)*128 + wr*64 + mi*16 + l15) * BK \
                                            + (((ks*4 + kg) ^ l7) * 8)]; \
  } while (0)

#define LDB_(dst, nb, nh) do { \
    _Pragma("unroll") for (int ni = 0; ni < 2; ++ni) \
    _Pragma("unroll") for (int ks = 0; ks < 2; ++ks) \
      dst[ni][ks] = *(const bf16x8*)&Bs[nb][((nh)*128 + wc*32 + ni*16 + l15) * BK \
                                            + (((ks*4 + kg) ^ l7) * 8)]; \
  } while (0)

#define QUAD(mh, nh, aR, bR) do { PRI1(); \
    _Pragma("unroll") for (int mi = 0; mi < 4; ++mi) \
    _Pragma("unroll") for (int ni = 0; ni < 2; ++ni) \
    _Pragma("unroll") for (int ks = 0; ks < 2; ++ks) \
      acc[(mh)*4 + mi][(nh)*2 + ni] = __builtin_amdgcn_mfma_f32_16x16x32_bf16( \
          aR[mi][ks], bR[ni][ks], acc[(mh)*4 + mi][(nh)*2 + ni], 0, 0, 0); \
    PRI0(); } while (0)

  // ---- prologue: stage tile0 -> buf0 and tile1 -> buf1 (16 loads) ----
  STAGE_A(0, 0, 0); STAGE_A(0, 1, 0);
  STAGE_B(0, 0, 0); STAGE_B(0, 1, 0);
  STAGE_A(1, 0, 1); STAGE_A(1, 1, 1);
  STAGE_B(1, 0, 1); STAGE_B(1, 1, 1);
  VMC(8); BARX();                   // tile0 landed; tile1's 8 in flight
  LDA_(aA, 0, 0); LDB_(b0, 0, 0);

  // ---- main loop: tiles 0..NT-3, staging t+2 ----
#pragma unroll 1
  for (int t = 0; t < NT - 2; ++t) {
    const int cur = t & 1, nxt = cur ^ 1;
    // P1
    LDB_(b1, cur, 1); LDA_(aB, cur, 1);
    QUAD(0, 0, aA, b0);
    BARX();                          // publishes A0,B0[cur] reads done
    // P2
    STAGE_A(t + 2, 0, cur); STAGE_B(t + 2, 0, cur);
    QUAD(0, 1, aA, b1);
    BARX();
    // P3
    QUAD(1, 1, aB, b1);
    BARX();                          // publishes A1,B1[cur] reads done
    // P4
    STAGE_A(t + 2, 1, cur); STAGE_B(t + 2, 1, cur);
    VMC(8);                          // drain tile t+1; keep t+2's 8 in flight
    BARX();                          // tile t+1 LDS ready for all waves
    QUAD(1, 0, aB, b0);
    LDA_(aA, nxt, 0); LDB_(b0, nxt, 0);   // reads for tile t+1 (WAR renamed)
  }

  // ---- peeled tile NT-2 (buf0): no staging; drain all ----
  LDB_(b1, 0, 1); LDA_(aB, 0, 1);
  QUAD(0, 0, aA, b0);
  BARX();
  QUAD(0, 1, aA, b1);
  BARX();
  QUAD(1, 1, aB, b1);
  BARX();
  VMC(0);
  BARX();
  QUAD(1, 0, aB, b0);
  LDA_(aA, 1, 0); LDB_(b0, 1, 0);

  // ---- peeled tile NT-1 (buf1): straight-line ----
  LDB_(b1, 1, 1); LDA_(aB, 1, 1);
  QUAD(0, 0, aA, b0);
  QUAD(0, 1, aA, b1);
  QUAD(1, 1, aB, b1);
  QUAD(1, 0, aB, b0);

#undef QUAD
#undef LDB_
#undef LDA_
#undef STAGE_B
#undef STAGE_A

  // ---- epilogue: row = mh*128 + wr*64 + mi*16 + kg*4 + v,
  //                col = nh*128 + wc*32 + ni*16 + l15
  float* yb = Y + (row0 + wr * 64 + kg * 4) * OUT_DIM + col0 + wc * 32 + l15;
#pragma unroll
  for (int mh = 0; mh < 2; ++mh)
#pragma unroll
    for (int mi = 0; mi < 4; ++mi)
#pragma unroll
      for (int nh = 0; nh < 2; ++nh)
#pragma unroll
        for (int ni = 0; ni < 2; ++ni)
#pragma unroll
          for (int v = 0; v < 4; ++v)
            yb[(size_t)(mh * 128 + mi * 16 + v) * OUT_DIM + nh * 128 + ni * 16] =
                acc[mh * 4 + mi][nh * 2 + ni][v];
}

// ---------------- fallback (ws too small): 128^2 fp32-A reg-staged ---------
__global__ void gemm_fb(const float* __restrict__ X, const ushort* __restrict__ W,
                        float* __restrict__ Y) {
  __shared__ ushort Af[128 * 64];
  __shared__ ushort Bf[128 * 64];
  const int tid  = threadIdx.x;
  const int lane = tid & 63;
  const int wid  = tid >> 6;
  const int wr   = wid >> 1, wc = wid & 1;
  const int bid  = blockIdx.x;
  const int tm   = bid / 32, tn = bid % 32;
  const size_t row0 = (size_t)tm * 128, col0 = (size_t)tn * 128;
  f32x4 acc[4][4] = {};
  const int arow = lane & 15, kgrp = lane >> 4;
  const int srow = lane >> 3, scol = (lane & 7) * 8;
  for (int k0 = 0; k0 < IN_DIM; k0 += 64) {
    f32x4 r[8];
#pragma unroll
    for (int i = 0; i < 8; ++i)
      r[i] = *(const f32x4*)(X + (row0 + i * 16 + (tid >> 4)) * IN_DIM + k0 + (tid & 15) * 4);
#pragma unroll
    for (int i = 0; i < 8; ++i) {
      bf16x4 o;
      o[0] = (short)f2bf(r[i][0]); o[1] = (short)f2bf(r[i][1]);
      o[2] = (short)f2bf(r[i][2]); o[3] = (short)f2bf(r[i][3]);
      *(bf16x4*)&Af[(i * 16 + (tid >> 4)) * 64 + (tid & 15) * 4] = o;
    }
#pragma unroll
    for (int i = 0; i < 4; ++i) {
      const int c = wid * 4 + i;
      llds16(W + (col0 + c * 8 + srow) * IN_DIM + k0 + scol, Bf + c * 512);
    }
    __syncthreads();
#pragma unroll
    for (int ks = 0; ks < 2; ++ks) {
      bf16x8 a[4], b[4];
#pragma unroll
      for (int m = 0; m < 4; ++m)
        a[m] = *(const bf16x8*)&Af[(wr * 64 + m * 16 + arow) * 64 + ks * 32 + kgrp * 8];
#pragma unroll
      for (int n = 0; n < 4; ++n)
        b[n] = *(const bf16x8*)&Bf[(wc * 64 + n * 16 + arow) * 64 + ks * 32 + kgrp * 8];
#pragma unroll
      for (int m = 0; m < 4; ++m)
#pragma unroll
        for (int n = 0; n < 4; ++n)
          acc[m][n] = __builtin_amdgcn_mfma_f32_16x16x32_bf16(a[m], b[n], acc[m][n], 0, 0, 0);
    }
    __syncthreads();
  }
  float* yb = Y + (row0 + wr * 64) * OUT_DIM + col0 + wc * 64;
  const int crow = (lane >> 4) * 4, ccol = lane & 15;
#pragma unroll
  for (int m = 0; m < 4; ++m)
#pragma unroll
    for (int n = 0; n < 4; ++n)
#pragma unroll
      for (int v = 0; v < 4; ++v)
        yb[(size_t)(m * 16 + crow + v) * OUT_DIM + n * 16 + ccol] = acc[m][n][v];
}

extern "C" void kernel_launch(void* const* d_in, const int* in_sizes, int n_in,
                              void* d_out, int out_size, void* d_ws, size_t ws_size,
                              hipStream_t stream) {
  const float* x  = (const float*)d_in[0];
  const int*   q  = (const int*)d_in[1];
  const float* am = (const float*)d_in[2];
  float* y = (float*)d_out;

  ushort* w = (ushort*)d_ws;
  const size_t WB = (size_t)OUT_DIM * IN_DIM * sizeof(ushort);   // 33.5 MB
  const size_t XB = (size_t)M_DIM * IN_DIM * sizeof(ushort);     // 134 MB

  dequant_nf4<<<(OUT_DIM * (size_t)IN_DIM) / 8 / 256, 256, 0, stream>>>(q, am, w);

  if (ws_size >= WB + XB) {
    ushort* xb = (ushort*)((char*)d_ws + WB);
    cvt_x<<<((size_t)M_DIM * IN_DIM) / 8 / 256, 256, 0, stream>>>(x, xb);
    gemm256<<<(M_DIM / 256) * (OUT_DIM / 256), 512, 0, stream>>>(xb, w, y);
  } else {
    gemm_fb<<<(M_DIM / 128) * (OUT_DIM / 128), 256, 0, stream>>>(x, w, y);
  }
}

// Round 5
// 616.342 us; speedup vs baseline: 1.0284x; 1.0284x over previous
//
#include <hip/hip_runtime.h>
#include <hip/hip_bf16.h>
#include <stdint.h>

#define IN_DIM  4096
#define OUT_DIM 4096
#define M_DIM   16384   // 8*2048
#define BK      64
#define NT      (IN_DIM / BK)   // 64

typedef float f32x4 __attribute__((ext_vector_type(4)));
typedef short bf16x8 __attribute__((ext_vector_type(8)));
typedef short bf16x4 __attribute__((ext_vector_type(4)));
typedef int   i32x4 __attribute__((ext_vector_type(4)));

__device__ __constant__ float NF4_CODE_D[16] = {
    -1.0f, -0.6961928009986877f, -0.5250730514526367f, -0.39491748809814453f,
    -0.28444138169288635f, -0.18477343022823334f, -0.09105003625154495f, 0.0f,
    0.07958029955625534f, 0.16093020141124725f, 0.24611230194568634f,
    0.33791524171829224f, 0.44070982933044434f, 0.5626170039176941f,
    0.7229568362236023f, 1.0f};

static __device__ __forceinline__ ushort f2bf(float f) {
  union { float f; uint32_t u; } v; v.f = f;
  uint32_t r = v.u + 0x7FFFu + ((v.u >> 16) & 1u);
  return (ushort)(r >> 16);
}

// ---------------- dequant: qweight(int32 0..15) * absmax -> bf16 W[N][K] ----
__global__ void dequant_nf4(const int* __restrict__ q, const float* __restrict__ am,
                            ushort* __restrict__ w) {
  __shared__ float code[16];
  if (threadIdx.x < 16) code[threadIdx.x] = NF4_CODE_D[threadIdx.x];
  __syncthreads();
  size_t t = (size_t)blockIdx.x * blockDim.x + threadIdx.x;
  size_t base = t * 8;
  i32x4 qa = *(const i32x4*)(q + base);
  i32x4 qb = *(const i32x4*)(q + base + 4);
  float s = am[base >> 6];
  bf16x8 o;
  o[0] = (short)f2bf(code[qa[0] & 15] * s);
  o[1] = (short)f2bf(code[qa[1] & 15] * s);
  o[2] = (short)f2bf(code[qa[2] & 15] * s);
  o[3] = (short)f2bf(code[qa[3] & 15] * s);
  o[4] = (short)f2bf(code[qb[0] & 15] * s);
  o[5] = (short)f2bf(code[qb[1] & 15] * s);
  o[6] = (short)f2bf(code[qb[2] & 15] * s);
  o[7] = (short)f2bf(code[qb[3] & 15] * s);
  *(bf16x8*)(w + base) = o;
}

// ---------------- x fp32 -> bf16 ----------------
__global__ void cvt_x(const float* __restrict__ x, ushort* __restrict__ xb) {
  size_t t = (size_t)blockIdx.x * blockDim.x + threadIdx.x;
  size_t base = t * 8;
  f32x4 a = *(const f32x4*)(x + base);
  f32x4 b = *(const f32x4*)(x + base + 4);
  bf16x8 o;
  o[0] = (short)f2bf(a[0]); o[1] = (short)f2bf(a[1]);
  o[2] = (short)f2bf(a[2]); o[3] = (short)f2bf(a[3]);
  o[4] = (short)f2bf(b[0]); o[5] = (short)f2bf(b[1]);
  o[6] = (short)f2bf(b[2]); o[7] = (short)f2bf(b[3]);
  *(bf16x8*)(xb + base) = o;
}

// ---------------- global_load_lds helper (16B direct-to-LDS) ---------------
static __device__ __forceinline__ void llds16(const ushort* g, ushort* l) {
  __builtin_amdgcn_global_load_lds(
      (const __attribute__((address_space(1))) void*)g,
      (__attribute__((address_space(3))) void*)l, 16, 0, 0);
}

// ===========================================================================
// 256x256 GEMM, m201-style 2-barrier phases.
// y[M][N] = Xb[M][K] * W[N][K]^T, bf16 MFMA 16x16x32, 8 waves (2Mx4N).
// Per-wave output rows {wr*64} U {128+wr*64}, cols {wc*32} U {128+wc*32};
// reg buffers: aA<->A0 half, aB<->A1, b0<->B0, b1<->B1 of current buffer.
// Phase = [reads | stage 1 half-tile | (waits) | BAR | lgkm0+schedbar |
//          16 MFMA (setprio1) | BAR]. Reads pinned above bar1 by asm memory
// clobber; MFMA cluster is wait-free => one wave's LDS drain overlaps other
// waves' MFMA (the T5/T3 mechanism). Quads: P1=Q00(aA,b0) P2=Q10(aB,b0)
// P3=Q01(aA,b1) P4=Q11(aB,b1). Reads one phase ahead:
//  R_P1: aB[cur](8)   R_P2: b1[cur](4)   R_P3: none
//  R_P4: aA[nxt](8)+b0[nxt](4)  (12 -> lgkmcnt(8) pre-drain)
// All fragment vars single-named: each is overwritten only after its last
// consuming quad (aA,b0 @R_P4 > M_P3/M_P2; aB,b1 @next tile > M_P4).
// Staging: tile t stages t+2 into cur, 1 half/phase {A0@P1,B0@P2,A1@P3,B1@P4}.
// WAR fences: each region's last ds_read drains at the lgkm0 of its quad-
// phase, a barrier follows, staging write issues after => fenced.
// vmcnt ledger (2 loads/stage-op): VMC(10)@R_P3 drains A0,B0(t+1) (staged
// P1/P2 of t-1, 5-6 phases flight) keeping {A1,B1(t+1),A0,B0,A1(t+2)}=10;
// VMC(8)@R_P4 drains A1,B1(t+1) keeping t+2's 8. Publication: vmcnt ->
// bar1 -> reads of that region (R_P4 reads nxt after P3's bar). Never
// vmcnt(0) in the loop.
// ===========================================================================
__global__ __launch_bounds__(512, 2) void gemm256(const ushort* __restrict__ Xb,
                                                  const ushort* __restrict__ W,
                                                  float* __restrict__ Y) {
  __shared__ ushort As[2][256 * BK];   // 2 x 32 KB
  __shared__ ushort Bs[2][256 * BK];   // 2 x 32 KB

  const int tid  = threadIdx.x;
  const int lane = tid & 63;
  const int wid  = tid >> 6;        // 0..7
  const int wr   = wid >> 2;        // 0..1
  const int wc   = wid & 3;         // 0..3
  const int l15  = lane & 15;
  const int kg   = lane >> 4;       // 0..3
  const int l7   = lane & 7;

  // bijective XCD swizzle (1024 wgs, 1024%8==0), tn-major within tm.
  const int bid = blockIdx.x;
  const int wg  = (bid & 7) * 128 + (bid >> 3);
  const int tm  = wg >> 4;          // 0..63
  const int tn  = wg & 15;          // 0..15
  const size_t row0 = (size_t)tm * 256;
  const size_t col0 = (size_t)tn * 256;

  const int srow  = tid >> 3;                       // 0..63
  const int scol8 = ((tid & 7) ^ (srow & 7)) * 8;   // pre-swizzled src col
  const int wbase = wid << 9;                       // wave LDS base (ushorts)

  f32x4  acc[8][4] = {};
  bf16x8 aA[4][2], aB[4][2], b0[2][2], b1[2][2];

#define BARX()   asm volatile("s_barrier" ::: "memory")
#define LGKM0()  do { asm volatile("s_waitcnt lgkmcnt(0)" ::: "memory"); \
                      __builtin_amdgcn_sched_barrier(0); } while (0)
#define LGKM8()  asm volatile("s_waitcnt lgkmcnt(8)" ::: "memory")
#define VMC(n)   asm volatile("s_waitcnt vmcnt(" #n ")" ::: "memory")
#define PRI1()   __builtin_amdgcn_s_setprio(1)
#define PRI0()   __builtin_amdgcn_s_setprio(0)

#define STAGE_A(kt, h, nb) do { \
    llds16(Xb + (row0 + (h)*128 +  0 + srow) * IN_DIM + (kt)*BK + scol8, \
           &As[nb][(h)*8192 +    0 + wbase]); \
    llds16(Xb + (row0 + (h)*128 + 64 + srow) * IN_DIM + (kt)*BK + scol8, \
           &As[nb][(h)*8192 + 4096 + wbase]); \
  } while (0)

#define STAGE_B(kt, h, nb) do { \
    llds16(W + (col0 + (h)*128 +  0 + srow) * IN_DIM + (kt)*BK + scol8, \
           &Bs[nb][(h)*8192 +    0 + wbase]); \
    llds16(W + (col0 + (h)*128 + 64 + srow) * IN_DIM + (kt)*BK + scol8, \
           &Bs[nb][(h)*8192 + 4096 + wbase]); \
  } while (0)

#define LDA_(dst, nb, mh) do { \
    _Pragma("unroll") for (int mi = 0; mi < 4; ++mi) \
    _Pragma("unroll") for (int ks = 0; ks < 2; ++ks) \
      dst[mi][ks] = *(const bf16x8*)&As[nb][((mh)*128 + wr*64 + mi*16 + l15) * BK \
                                            + (((ks*4 + kg) ^ l7) * 8)]; \
  } while (0)

#define LDB_(dst, nb, nh) do { \
    _Pragma("unroll") for (int ni = 0; ni < 2; ++ni) \
    _Pragma("unroll") for (int ks = 0; ks < 2; ++ks) \
      dst[ni][ks] = *(const bf16x8*)&Bs[nb][((nh)*128 + wc*32 + ni*16 + l15) * BK \
                                            + (((ks*4 + kg) ^ l7) * 8)]; \
  } while (0)

#define QUAD(mh, nh, aR, bR) do { PRI1(); \
    _Pragma("unroll") for (int mi = 0; mi < 4; ++mi) \
    _Pragma("unroll") for (int ni = 0; ni < 2; ++ni) \
    _Pragma("unroll") for (int ks = 0; ks < 2; ++ks) \
      acc[(mh)*4 + mi][(nh)*2 + ni] = __builtin_amdgcn_mfma_f32_16x16x32_bf16( \
          aR[mi][ks], bR[ni][ks], acc[(mh)*4 + mi][(nh)*2 + ni], 0, 0, 0); \
    PRI0(); } while (0)

  // ---- prologue: stage tiles 0,1 (order A0,B0,A1,B1 each); pre-read Q00 ----
  STAGE_A(0, 0, 0); STAGE_B(0, 0, 0); STAGE_A(0, 1, 0); STAGE_B(0, 1, 0);
  STAGE_A(1, 0, 1); STAGE_B(1, 0, 1); STAGE_A(1, 1, 1); STAGE_B(1, 1, 1);
  VMC(8); BARX();                   // tile0 landed; tile1's 8 in flight
  LDA_(aA, 0, 0); LDB_(b0, 0, 0);  // 12 reads for M_P1(0)

  // ---- main loop: tiles 0..NT-3, staging t+2 into cur ----
#pragma unroll 1
  for (int t = 0; t < NT - 2; ++t) {
    const int cur = t & 1, nxt = cur ^ 1;
    // P1
    LDA_(aB, cur, 1);
    STAGE_A(t + 2, 0, cur);
    BARX(); LGKM0();
    QUAD(0, 0, aA, b0);
    BARX();
    // P2
    LDB_(b1, cur, 1);
    STAGE_B(t + 2, 0, cur);
    BARX(); LGKM0();
    QUAD(1, 0, aB, b0);
    BARX();
    // P3
    STAGE_A(t + 2, 1, cur);
    VMC(10);                         // drain A0,B0(t+1); publish via bar1
    BARX(); LGKM0();
    QUAD(0, 1, aA, b1);
    BARX();
    // P4
    LDA_(aA, nxt, 0); LDB_(b0, nxt, 0);   // 12 reads for next tile's Q00
    STAGE_B(t + 2, 1, cur);
    LGKM8();                         // pre-drain first 8 of the 12
    VMC(8);                          // drain A1,B1(t+1)
    BARX(); LGKM0();
    QUAD(1, 1, aB, b1);
    BARX();
  }

  // ---- peeled tile NT-2 (cur=0): no staging; drain remaining ----
  LDA_(aB, 0, 1);
  BARX(); LGKM0();
  QUAD(0, 0, aA, b0);
  BARX();
  LDB_(b1, 0, 1);
  BARX(); LGKM0();
  QUAD(1, 0, aB, b0);
  BARX();
  VMC(4);                            // drain A0,B0(NT-1)
  BARX(); LGKM0();
  QUAD(0, 1, aA, b1);
  BARX();
  LDA_(aA, 1, 0); LDB_(b0, 1, 0);
  LGKM8(); VMC(0);                   // drain A1,B1(NT-1)
  BARX(); LGKM0();
  QUAD(1, 1, aB, b1);
  BARX();

  // ---- peeled tile NT-1 (cur=1): straight-line, compiler-managed waits ----
  LDA_(aB, 1, 1); LDB_(b1, 1, 1);
  QUAD(0, 0, aA, b0);
  QUAD(1, 0, aB, b0);
  QUAD(0, 1, aA, b1);
  QUAD(1, 1, aB, b1);

#undef QUAD
#undef LDB_
#undef LDA_
#undef STAGE_B
#undef STAGE_A

  // ---- epilogue: row = mh*128 + wr*64 + mi*16 + kg*4 + v,
  //                col = nh*128 + wc*32 + ni*16 + l15
  float* yb = Y + (row0 + wr * 64 + kg * 4) * OUT_DIM + col0 + wc * 32 + l15;
#pragma unroll
  for (int mh = 0; mh < 2; ++mh)
#pragma unroll
    for (int mi = 0; mi < 4; ++mi)
#pragma unroll
      for (int nh = 0; nh < 2; ++nh)
#pragma unroll
        for (int ni = 0; ni < 2; ++ni)
#pragma unroll
          for (int v = 0; v < 4; ++v)
            yb[(size_t)(mh * 128 + mi * 16 + v) * OUT_DIM + nh * 128 + ni * 16] =
                acc[mh * 4 + mi][nh * 2 + ni][v];
}

// ---------------- fallback (ws too small): 128^2 fp32-A reg-staged ---------
__global__ void gemm_fb(const float* __restrict__ X, const ushort* __restrict__ W,
                        float* __restrict__ Y) {
  __shared__ ushort Af[128 * 64];
  __shared__ ushort Bf[128 * 64];
  const int tid  = threadIdx.x;
  const int lane = tid & 63;
  const int wid  = tid >> 6;
  const int wr   = wid >> 1, wc = wid & 1;
  const int bid  = blockIdx.x;
  const int tm   = bid / 32, tn = bid % 32;
  const size_t row0 = (size_t)tm * 128, col0 = (size_t)tn * 128;
  f32x4 acc[4][4] = {};
  const int arow = lane & 15, kgrp = lane >> 4;
  const int srow = lane >> 3, scol = (lane & 7) * 8;
  for (int k0 = 0; k0 < IN_DIM; k0 += 64) {
    f32x4 r[8];
#pragma unroll
    for (int i = 0; i < 8; ++i)
      r[i] = *(const f32x4*)(X + (row0 + i * 16 + (tid >> 4)) * IN_DIM + k0 + (tid & 15) * 4);
#pragma unroll
    for (int i = 0; i < 8; ++i) {
      bf16x4 o;
      o[0] = (short)f2bf(r[i][0]); o[1] = (short)f2bf(r[i][1]);
      o[2] = (short)f2bf(r[i][2]); o[3] = (short)f2bf(r[i][3]);
      *(bf16x4*)&Af[(i * 16 + (tid >> 4)) * 64 + (tid & 15) * 4] = o;
    }
#pragma unroll
    for (int i = 0; i < 4; ++i) {
      const int c = wid * 4 + i;
      llds16(W + (col0 + c * 8 + srow) * IN_DIM + k0 + scol, Bf + c * 512);
    }
    __syncthreads();
#pragma unroll
    for (int ks = 0; ks < 2; ++ks) {
      bf16x8 a[4], b[4];
#pragma unroll
      for (int m = 0; m < 4; ++m)
        a[m] = *(const bf16x8*)&Af[(wr * 64 + m * 16 + arow) * 64 + ks * 32 + kgrp * 8];
#pragma unroll
      for (int n = 0; n < 4; ++n)
        b[n] = *(const bf16x8*)&Bf[(wc * 64 + n * 16 + arow) * 64 + ks * 32 + kgrp * 8];
#pragma unroll
      for (int m = 0; m < 4; ++m)
#pragma unroll
        for (int n = 0; n < 4; ++n)
          acc[m][n] = __builtin_amdgcn_mfma_f32_16x16x32_bf16(a[m], b[n], acc[m][n], 0, 0, 0);
    }
    __syncthreads();
  }
  float* yb = Y + (row0 + wr * 64) * OUT_DIM + col0 + wc * 64;
  const int crow = (lane >> 4) * 4, ccol = lane & 15;
#pragma unroll
  for (int m = 0; m < 4; ++m)
#pragma unroll
    for (int n = 0; n < 4; ++n)
#pragma unroll
      for (int v = 0; v < 4; ++v)
        yb[(size_t)(m * 16 + crow + v) * OUT_DIM + n * 16 + ccol] = acc[m][n][v];
}

extern "C" void kernel_launch(void* const* d_in, const int* in_sizes, int n_in,
                              void* d_out, int out_size, void* d_ws, size_t ws_size,
                              hipStream_t stream) {
  const float* x  = (const float*)d_in[0];
  const int*   q  = (const int*)d_in[1];
  const float* am = (const float*)d_in[2];
  float* y = (float*)d_out;

  ushort* w = (ushort*)d_ws;
  const size_t WB = (size_t)OUT_DIM * IN_DIM * sizeof(ushort);   // 33.5 MB
  const size_t XB = (size_t)M_DIM * IN_DIM * sizeof(ushort);     // 134 MB

  dequant_nf4<<<(OUT_DIM * (size_t)IN_DIM) / 8 / 256, 256, 0, stream>>>(q, am, w);

  if (ws_size >= WB + XB) {
    ushort* xb = (ushort*)((char*)d_ws + WB);
    cvt_x<<<((size_t)M_DIM * IN_DIM) / 8 / 256, 256, 0, stream>>>(x, xb);
    gemm256<<<(M_DIM / 256) * (OUT_DIM / 256), 512, 0, stream>>>(xb, w, y);
  } else {
    gemm_fb<<<(M_DIM / 128) * (OUT_DIM / 128), 256, 0, stream>>>(x, w, y);
  }
}